// Round 5
// baseline (296.430 us; speedup 1.0000x reference)
//
#include <hip/hip_runtime.h>
#include <stdint.h>

#define N_THRESH 100
#define NBINS 101
#define NSUB 8
#define STEP_ELEMS 2048                 // elements per buffer step per block
#define STEPS 8
#define TILE_ELEMS (STEP_ELEMS * STEPS) // 16384 per block-tile

typedef __attribute__((address_space(3))) uint32_t lds_u32_t;
typedef __attribute__((address_space(1))) uint32_t glob_u32_t;

// ---------------------------------------------------------------------------
// Kernel 0: zero the workspace histogram (d_ws is poisoned 0xAA every call).
// ---------------------------------------------------------------------------
__global__ void zero_ws_kernel(unsigned long long* __restrict__ ws) {
    int i = threadIdx.x;
    if (i < NBINS) ws[i] = 0ull;
}

// ---------------------------------------------------------------------------
// Branch-free exact bin (proven absmax 0.0 in R1-R4): cnt = searchsorted(
// thresholds, v, 'left'), thresholds[k] = float32(double(k)*0.01).
// e = trunc(fl(v*100)) is within 1 of the answer, so
// cnt = e + (t_e < v) + (t_{e+1} < v) exactly. All in registers.
// ---------------------------------------------------------------------------
__device__ __forceinline__ int bin_of(float v) {
    int e = (int)(v * 100.0f);
    e = e < 0 ? 0 : (e > 99 ? 99 : e);
    double ed = (double)e * 0.01;
    float t0 = (float)ed;
    float t1 = (float)(ed + 0.01);
    int c = e + (t0 < v ? 1 : 0) + (t1 < v ? 1 : 0);
    return c > N_THRESH ? N_THRESH : c;
}

__device__ __forceinline__ void acc4(unsigned int* __restrict__ h,
                                     float4 p, int4 g) {
    atomicAdd(&h[bin_of(p.x)], 1u | ((unsigned int)(g.x != 0) << 16));
    atomicAdd(&h[bin_of(p.y)], 1u | ((unsigned int)(g.y != 0) << 16));
    atomicAdd(&h[bin_of(p.z)], 1u | ((unsigned int)(g.z != 0) << 16));
    atomicAdd(&h[bin_of(p.w)], 1u | ((unsigned int)(g.w != 0) << 16));
}

// Async DMA: stage STEP_ELEMS pred floats + gt ints into LDS. Each wave
// stages its 512-element slice with 4 global_load_lds width=16 (dest =
// wave-uniform base + lane*16, matching the contiguous src layout).
__device__ __forceinline__ void stage(const float* __restrict__ pred,
                                      const int* __restrict__ gt,
                                      float* sp, int* sg,
                                      int ebase, int wave, int lane) {
    const float* srcp = pred + ebase + wave * 512 + lane * 4;
    const int*   srcg = gt   + ebase + wave * 512 + lane * 4;
    lds_u32_t* dp = (lds_u32_t*)(sp + wave * 512);
    lds_u32_t* dg = (lds_u32_t*)(sg + wave * 512);
    __builtin_amdgcn_global_load_lds((glob_u32_t*)srcp,         dp,       16, 0, 0);
    __builtin_amdgcn_global_load_lds((glob_u32_t*)(srcp + 256), dp + 256, 16, 0, 0);
    __builtin_amdgcn_global_load_lds((glob_u32_t*)srcg,         dg,       16, 0, 0);
    __builtin_amdgcn_global_load_lds((glob_u32_t*)(srcg + 256), dg + 256, 16, 0, 0);
}

// ---------------------------------------------------------------------------
// Kernel 1: DMA-staged streaming histogram.
// LDS: 2 x (8KB pred + 8KB gt) double buffer + 3.2KB hist = 35.5KB
//   -> 4 blocks/CU resident, up to 64KB DMA in flight per CU (vs 2KB with
//      VGPR-held loads = the 1.35 TB/s wall of R1-R4).
// ---------------------------------------------------------------------------
__global__ __launch_bounds__(256) void hist_kernel(
        const float* __restrict__ pred,
        const int* __restrict__ gt,
        unsigned long long* __restrict__ ws,
        int n) {
    __shared__ __align__(16) float sp[2][STEP_ELEMS];
    __shared__ __align__(16) int   sg[2][STEP_ELEMS];
    __shared__ unsigned int hist[NSUB][NBINS];

    const int tid  = threadIdx.x;
    const int wave = tid >> 6;
    const int lane = tid & 63;
    const int sub  = (wave << 1) | (tid & 1);
    unsigned int* __restrict__ h = hist[sub];

    for (int i = tid; i < NSUB * NBINS; i += 256)
        (&hist[0][0])[i] = 0u;

    for (long long tile = blockIdx.x; tile * TILE_ELEMS < n; tile += gridDim.x) {
        int base = (int)(tile * TILE_ELEMS);
        if (base + TILE_ELEMS <= n) {
            // fast path: full tile via DMA double-buffer
            stage(pred, gt, sp[0], sg[0], base, wave, lane);
            __syncthreads();   // drain vmcnt: buf0 landed (also covers zero-init)
            for (int s = 0; s < STEPS; ++s) {
                int nb = s & 1;
                if (s + 1 < STEPS)
                    stage(pred, gt, sp[nb ^ 1], sg[nb ^ 1],
                          base + (s + 1) * STEP_ELEMS, wave, lane);
                const float4* pb = (const float4*)&sp[nb][0];
                const int4*   gb = (const int4*)&sg[nb][0];
                float4 a  = pb[tid * 2];
                float4 b  = pb[tid * 2 + 1];
                int4   ga = gb[tid * 2];
                int4   gbv = gb[tid * 2 + 1];
                acc4(h, a, ga);
                acc4(h, b, gbv);
                __syncthreads();  // prefetch landed + buffer reads done
            }
        } else {
            // general tail path (empty for N = 2^25)
            for (int k = base + tid; k < n; k += 256) {
                atomicAdd(&h[bin_of(pred[k])],
                          1u | ((unsigned int)(gt[k] != 0) << 16));
            }
            __syncthreads();
        }
    }

    __syncthreads();
    if (tid < NBINS) {
        unsigned long long cnt = 0ull, pos = 0ull;
#pragma unroll
        for (int w = 0; w < NSUB; ++w) {
            unsigned int v = hist[w][tid];
            cnt += v & 0xffffu;
            pos += v >> 16;
        }
        unsigned long long s = (pos << 32) | cnt;
        if (s) atomicAdd(&ws[tid], s);
    }
}

// ---------------------------------------------------------------------------
// Kernel 2: suffix sums + IoU. One block, trivial cost.
// out[0:100] = thresholds, out[100:200] = ious.
// ---------------------------------------------------------------------------
__global__ void finalize_kernel(const unsigned long long* __restrict__ ws,
                                float* __restrict__ out) {
    __shared__ unsigned int pos[NBINS], all[NBINS];
    int k = threadIdx.x;
    if (k < NBINS) {
        unsigned long long h = ws[k];
        pos[k] = (unsigned int)(h >> 32);
        all[k] = (unsigned int)(h & 0xffffffffull);
    }
    __syncthreads();
    if (k < N_THRESH) {
        out[k] = (float)((double)k * 0.01);
        unsigned long long tp = 0, pp = 0, ngt = 0;
        for (int c = k + 1; c <= N_THRESH; ++c) { tp += pos[c]; pp += all[c]; }
        for (int c = 0; c <= N_THRESH; ++c) ngt += pos[c];
        long long uni = (long long)(pp + ngt - tp);   // TP + FP + FN
        double iou = (uni > 0) ? (double)tp / (double)uni : 0.0;
        out[N_THRESH + k] = (float)iou;
    }
}

// ---------------------------------------------------------------------------
extern "C" void kernel_launch(void* const* d_in, const int* in_sizes, int n_in,
                              void* d_out, int out_size, void* d_ws, size_t ws_size,
                              hipStream_t stream) {
    const float* pred = (const float*)d_in[0];
    const int*   gt   = (const int*)d_in[1];
    float* out = (float*)d_out;
    unsigned long long* ws = (unsigned long long*)d_ws;
    int n = in_sizes[0];

    zero_ws_kernel<<<1, 128, 0, stream>>>(ws);
    // 2048 blocks: one 16384-element tile per block at N = 2^25
    hist_kernel<<<2048, 256, 0, stream>>>(pred, gt, ws, n);
    finalize_kernel<<<1, 128, 0, stream>>>(ws, out);
}